// Round 12
// baseline (110.615 us; speedup 1.0000x reference)
//
#include <hip/hip_runtime.h>

// Problem constants (fixed by the reference)
#define BATCH   32
#define C_OUT_N 128
#define NK      5
#define C_IN_N  (NK * C_OUT_N)   // 640
#define HIN     58
#define WIN     58
#define HOUT    56
#define WOUT    56
#define NPIX    (HOUT * WOUT)                       // 3136
#define NTILE   (HOUT * (WOUT / 8))                 // 392 8-px tiles
#define OUT_PLANE ((size_t)BATCH * C_OUT_N * NPIX)  // 12,845,056

// Shift set fixed: REAL_PAD[t] = 4 - 3*t -> {4,1,-2,-5,-8}
// LDS: f16 [NK][59][68]; row 58 of each channel is ALL ZERO (v-tap OOB target).
// Data rows: x col c at idx 7+c; zeros at idx 0..6 and 65..67.
// Window for 8-px tile (h,w0): idx (h+1)*68 + w0 + [0..19]; all b64 aligned
// (CH_STRIDE=4012 and 68 are mult of 4; w0 mult of 8).
// LDS = 5*59*68*2 = 40,120 B -> 4 blocks/CU; 512 threads -> ~32 waves/CU.
#define NTHREADS    512
#define LDS_STRIDE  68                       // f16 elements
#define ROWS_PER_CH 59                       // 58 data + 1 zero row
#define CH_STRIDE   (ROWS_PER_CH * LDS_STRIDE)  // 4012
#define LDS_HALVES  (NK * CH_STRIDE)         // 20,060 -> 40,120 B
#define NV4         (NK * HIN * WIN / 4)     // 4205 float4s per (b,co) chunk
#define ZMARG       (LDS_STRIDE + HIN * 10)  // 648 zeroed ushorts per channel

typedef _Float16 h2 __attribute__((ext_vector_type(2)));
typedef _Float16 h4 __attribute__((ext_vector_type(4)));

static __device__ __forceinline__ unsigned int h2u(h2 v) {
    unsigned int r; __builtin_memcpy(&r, &v, 4); return r;
}
static __device__ __forceinline__ h2 uh2(unsigned int u) {
    h2 r; __builtin_memcpy(&r, &u, 4); return r;
}
// shifted-by-one-column f16 pair via v_alignbit_b32
static __device__ __forceinline__ h2 algn(h2 lo, h2 hi) {
    return uh2(__builtin_amdgcn_alignbit(h2u(hi), h2u(lo), 16));
}
// packed f32x2 -> f16x2 (round-toward-zero), bit-cast to our h2 type
static __device__ __forceinline__ h2 pkrtz(float a, float b) {
    auto t = __builtin_amdgcn_cvt_pkrtz(a, b);   // __fp16 ext_vector(2)
    h2 r; __builtin_memcpy(&r, &t, 4); return r;
}

__global__ __launch_bounds__(NTHREADS, 8) void addshift_bl_kernel(
    const float* __restrict__ x,          // (B, C_IN, 58, 58)
    const int*   __restrict__ pad_hv,     // (C_IN, 8): [0..3]=h shifts, [4..7]=v shifts
    const int*   __restrict__ idx_id,     // (C_OUT, 4), values in [co*5, co*5+5)
    float*       __restrict__ out)        // out_h | out_v | out_id concatenated
{
    extern __shared__ _Float16 lds[];

    const int bc  = blockIdx.x;           // b * C_OUT + co
    const int b   = bc / C_OUT_N;
    const int co  = bc - b * C_OUT_N;
    const int tid = threadIdx.x;

    // ---- zero: per channel, row 58 entirely + column margins of rows 0..57
    for (int i = tid; i < NK * ZMARG; i += NTHREADS) {
        int k = i / ZMARG;
        int m = i - k * ZMARG;
        int idx;
        if (m < LDS_STRIDE) {
            idx = k * CH_STRIDE + 58 * LDS_STRIDE + m;          // zero row
        } else {
            int mm  = m - LDS_STRIDE;
            int row = mm / 10;
            int c10 = mm - row * 10;
            int c   = (c10 < 7) ? c10 : (58 + c10);             // 0..6, 65..67
            idx = k * CH_STRIDE + row * LDS_STRIDE + c;
        }
        lds[idx] = (_Float16)0.f;
    }

    // ---- stage 5-channel chunk: float4 global loads -> f16 LDS (pkrtz)
    const float* xbase = x + (size_t)(b * C_IN_N + co * NK) * (HIN * WIN);
    for (int i = tid; i < NV4; i += NTHREADS) {
        int g = 4 * i;
        float4 v = *(const float4*)(xbase + g);
        int r  = g / 58;                  // global row 0..289 (magic mul)
        int c  = g - r * 58;              // even, 0..56
        int k  = r / 58;
        int lr = r - k * 58;
        _Float16* dst = &lds[k * CH_STRIDE + lr * LDS_STRIDE + 7 + c];
        if (c <= 54) {
            dst[0] = (_Float16)v.x;
            *(h2*)(dst + 1) = pkrtz(v.y, v.z);   // even idx, b32 write
            dst[3] = (_Float16)v.w;
        } else {                          // c == 56: last 2 floats wrap to next row
            dst[0] = (_Float16)v.x;
            dst[1] = (_Float16)v.y;
            int r2 = r + 1;               // never exceeds 289 (c==56 only at even r)
            int k2 = r2 / 58;
            int l2 = r2 - k2 * 58;
            _Float16* d2 = &lds[k2 * CH_STRIDE + l2 * LDS_STRIDE + 7];
            d2[0] = (_Float16)v.z;
            d2[1] = (_Float16)v.w;
        }
    }

    // ---- block-uniform shift multiplicities -> packed h2 weights in SGPRs
    float mhf[NK][5], mvf[NK][5], cntf[NK];
    #pragma unroll
    for (int k = 0; k < NK; ++k) {
        #pragma unroll
        for (int t = 0; t < 5; ++t) { mhf[k][t] = 0.f; mvf[k][t] = 0.f; }
        cntf[k] = 0.f;
        #pragma unroll
        for (int g = 0; g < 4; ++g) {
            int sh_v = pad_hv[(co * NK + k) * 8 + g];       // in {4,1,-2,-5,-8}
            int th   = (4 - sh_v) / 3;                      // slot 0..4
            int sv_v = pad_hv[(co * NK + k) * 8 + 4 + g];
            int tv   = (4 - sv_v) / 3;
            #pragma unroll
            for (int t = 0; t < 5; ++t) {
                mhf[k][t] += (th == t) ? 1.f : 0.f;
                mvf[k][t] += (tv == t) ? 1.f : 0.f;
            }
        }
    }
    #pragma unroll
    for (int g = 0; g < 4; ++g) {
        int c = idx_id[co * 4 + g] - co * NK;               // 0..4
        #pragma unroll
        for (int k = 0; k < NK; ++k) cntf[k] += (c == k) ? 1.f : 0.f;
    }
    unsigned int swh[NK][5], swv[NK][5], swc[NK];
    #pragma unroll
    for (int k = 0; k < NK; ++k) {
        #pragma unroll
        for (int t = 0; t < 5; ++t) {
            _Float16 a  = (_Float16)mhf[k][t];
            _Float16 b2 = (_Float16)mvf[k][t];
            h2 pa = {a, a}, pb = {b2, b2};
            swh[k][t] = __builtin_amdgcn_readfirstlane(h2u(pa));
            swv[k][t] = __builtin_amdgcn_readfirstlane(h2u(pb));
        }
        _Float16 cc = (_Float16)cntf[k];
        h2 pc = {cc, cc};
        swc[k] = __builtin_amdgcn_readfirstlane(h2u(pc));
    }

    __syncthreads();

    // ---- compute: one 8-px tile per thread, fully branchless, b64 + pk-FMA
    const int q = tid;
    if (q < NTILE) {
        const int h  = q / 7;
        const int w0 = 8 * (q - h * 7);

        // v-tap rows, OOB redirected to the per-channel zero row (58)
        int voff[5];
        #pragma unroll
        for (int t = 0; t < 5; ++t) {
            int rr = h + 5 - 3 * t;
            int rv = ((unsigned)rr < 58u) ? rr : 58;
            voff[t] = rv * LDS_STRIDE + w0 + 8;
        }
        const int rowbase = (h + 1) * LDS_STRIDE + w0;

        h2 sh[4], sv[4], si[4];
        #pragma unroll
        for (int m = 0; m < 4; ++m) {
            sh[m] = h2{(_Float16)0.f, (_Float16)0.f};
            sv[m] = sh[m]; si[m] = sh[m];
        }

        #pragma unroll
        for (int k = 0; k < NK; ++k) {
            const _Float16* chp  = lds + k * CH_STRIDE;
            const _Float16* rowp = chp + rowbase;

            // 20-col window: 5 x ds_read_b64 -> 10 f16-pairs
            h2 H[10];
            #pragma unroll
            for (int m = 0; m < 5; ++m) {
                h4 w = *(const h4*)(rowp + 4 * m);
                __builtin_memcpy(&H[2 * m],     &w, 4);
                __builtin_memcpy(&H[2 * m + 1], (const char*)&w + 4, 4);
            }

            // out_h: taps t=4..0 -> j = 0,3,6,9,12 (odd j via alignbit)
            #pragma unroll
            for (int m = 0; m < 4; ++m) sh[m] += uh2(swh[k][4]) * H[m];
            #pragma unroll
            for (int m = 0; m < 4; ++m) sh[m] += uh2(swh[k][3]) * algn(H[1 + m], H[2 + m]);
            #pragma unroll
            for (int m = 0; m < 4; ++m) sh[m] += uh2(swh[k][2]) * H[3 + m];
            #pragma unroll
            for (int m = 0; m < 4; ++m) sh[m] += uh2(swh[k][1]) * algn(H[4 + m], H[5 + m]);
            #pragma unroll
            for (int m = 0; m < 4; ++m) sh[m] += uh2(swh[k][0]) * H[6 + m];

            // out_id: center cols 8..15 = H[4..7]
            #pragma unroll
            for (int m = 0; m < 4; ++m) si[m] += uh2(swc[k]) * H[4 + m];

            // out_v: 2 x b64 per tap; OOB rows read zeros (weight irrelevant)
            #pragma unroll
            for (int t = 0; t < 5; ++t) {
                const _Float16* vp = chp + voff[t];
                h4 a  = *(const h4*)(vp);
                h4 b4 = *(const h4*)(vp + 4);
                h2 V0, V1, V2, V3;
                __builtin_memcpy(&V0, &a, 4);
                __builtin_memcpy(&V1, (const char*)&a + 4, 4);
                __builtin_memcpy(&V2, &b4, 4);
                __builtin_memcpy(&V3, (const char*)&b4 + 4, 4);
                h2 wv = uh2(swv[k][t]);
                sv[0] += wv * V0; sv[1] += wv * V1;
                sv[2] += wv * V2; sv[3] += wv * V3;
            }
        }

        size_t o = (size_t)bc * NPIX + h * WOUT + w0;
        *(float4*)(out + o) =
            make_float4((float)sh[0].x, (float)sh[0].y, (float)sh[1].x, (float)sh[1].y);
        *(float4*)(out + o + 4) =
            make_float4((float)sh[2].x, (float)sh[2].y, (float)sh[3].x, (float)sh[3].y);
        *(float4*)(out + OUT_PLANE + o) =
            make_float4((float)sv[0].x, (float)sv[0].y, (float)sv[1].x, (float)sv[1].y);
        *(float4*)(out + OUT_PLANE + o + 4) =
            make_float4((float)sv[2].x, (float)sv[2].y, (float)sv[3].x, (float)sv[3].y);
        *(float4*)(out + 2 * OUT_PLANE + o) =
            make_float4((float)si[0].x, (float)si[0].y, (float)si[1].x, (float)si[1].y);
        *(float4*)(out + 2 * OUT_PLANE + o + 4) =
            make_float4((float)si[2].x, (float)si[2].y, (float)si[3].x, (float)si[3].y);
    }
}

extern "C" void kernel_launch(void* const* d_in, const int* in_sizes, int n_in,
                              void* d_out, int out_size, void* d_ws, size_t ws_size,
                              hipStream_t stream) {
    const float* x      = (const float*)d_in[0];
    const int*   pad_hv = (const int*)d_in[1];
    const int*   idx_id = (const int*)d_in[2];
    float*       out    = (float*)d_out;

    addshift_bl_kernel<<<dim3(BATCH * C_OUT_N), dim3(NTHREADS),
                         LDS_HALVES * 2, stream>>>(x, pad_hv, idx_id, out);
}

// Round 13
// 109.188 us; speedup vs baseline: 1.0131x; 1.0131x over previous
//
#include <hip/hip_runtime.h>

// Problem constants (fixed by the reference)
#define BATCH   32
#define C_OUT_N 128
#define NK      5
#define C_IN_N  (NK * C_OUT_N)   // 640
#define HIN     58
#define WIN     58
#define HOUT    56
#define WOUT    56
#define NPIX    (HOUT * WOUT)                       // 3136
#define NTILE   (HOUT * (WOUT / 8))                 // 392 8-px tiles
#define OUT_PLANE ((size_t)BATCH * C_OUT_N * NPIX)  // 12,845,056

// Shift set fixed: REAL_PAD[t] = 4 - 3*t -> {4,1,-2,-5,-8}
// LDS: f16 [NK][59][68]; row 58 of each channel is ALL ZERO (v-tap OOB target).
// Data rows: x col c at idx 7+c; zeros at idx 0..6 and 65..67.
// Window for 8-px tile (h,w0): idx (h+1)*68 + w0 + [0..19]; all b64 aligned.
// b64 @ stride 68: lane->bank map {2r+4c mod 32} is a uniform 4/bank spread =
// data-movement minimum; SQ_LDS_BANK_CONFLICT here is intrinsic, not layout.
// LDS = 5*59*68*2 = 40,120 B -> 4 blocks/CU; 512 threads -> ~32 waves/CU.
#define NTHREADS    512
#define LDS_STRIDE  68                       // f16 elements
#define ROWS_PER_CH 59                       // 58 data + 1 zero row
#define CH_STRIDE   (ROWS_PER_CH * LDS_STRIDE)  // 4012
#define LDS_HALVES  (NK * CH_STRIDE)         // 20,060 -> 40,120 B
#define NV4         (NK * HIN * WIN / 4)     // 4205 float4s per (b,co) chunk
#define ZMARG       (LDS_STRIDE + HIN * 10)  // 648 zeroed ushorts per channel

typedef _Float16 h2 __attribute__((ext_vector_type(2)));
typedef _Float16 h4 __attribute__((ext_vector_type(4)));

static __device__ __forceinline__ unsigned int h2u(h2 v) {
    unsigned int r; __builtin_memcpy(&r, &v, 4); return r;
}
static __device__ __forceinline__ h2 uh2(unsigned int u) {
    h2 r; __builtin_memcpy(&r, &u, 4); return r;
}
// shifted-by-one-column f16 pair via v_alignbit_b32
static __device__ __forceinline__ h2 algn(h2 lo, h2 hi) {
    return uh2(__builtin_amdgcn_alignbit(h2u(hi), h2u(lo), 16));
}
// packed f32x2 -> f16x2 (round-toward-zero), bit-cast to our h2 type
static __device__ __forceinline__ h2 pkrtz(float a, float b) {
    auto t = __builtin_amdgcn_cvt_pkrtz(a, b);   // __fp16 ext_vector(2)
    h2 r; __builtin_memcpy(&r, &t, 4); return r;
}

__global__ __launch_bounds__(NTHREADS, 8) void addshift_bb_kernel(
    const float* __restrict__ x,          // (B, C_IN, 58, 58)
    const int*   __restrict__ pad_hv,     // (C_IN, 8): [0..3]=h shifts, [4..7]=v shifts
    const int*   __restrict__ idx_id,     // (C_OUT, 4), values in [co*5, co*5+5)
    float*       __restrict__ out)        // out_h | out_v | out_id concatenated
{
    extern __shared__ _Float16 lds[];

    const int bc  = blockIdx.x;           // b * C_OUT + co
    const int b   = bc / C_OUT_N;
    const int co  = bc - b * C_OUT_N;
    const int tid = threadIdx.x;

    // ---- zero: per channel, row 58 entirely + column margins of rows 0..57
    for (int i = tid; i < NK * ZMARG; i += NTHREADS) {
        int k = i / ZMARG;
        int m = i - k * ZMARG;
        int idx;
        if (m < LDS_STRIDE) {
            idx = k * CH_STRIDE + 58 * LDS_STRIDE + m;          // zero row
        } else {
            int mm  = m - LDS_STRIDE;
            int row = mm / 10;
            int c10 = mm - row * 10;
            int c   = (c10 < 7) ? c10 : (58 + c10);             // 0..6, 65..67
            idx = k * CH_STRIDE + row * LDS_STRIDE + c;
        }
        lds[idx] = (_Float16)0.f;
    }

    // ---- stage 5-channel chunk: float4 global loads -> f16 LDS (pkrtz)
    const float* xbase = x + (size_t)(b * C_IN_N + co * NK) * (HIN * WIN);
    for (int i = tid; i < NV4; i += NTHREADS) {
        int g = 4 * i;
        float4 v = *(const float4*)(xbase + g);
        int r  = g / 58;                  // global row 0..289 (magic mul)
        int c  = g - r * 58;              // even, 0..56
        int k  = r / 58;
        int lr = r - k * 58;
        _Float16* dst = &lds[k * CH_STRIDE + lr * LDS_STRIDE + 7 + c];
        if (c <= 54) {
            dst[0] = (_Float16)v.x;
            *(h2*)(dst + 1) = pkrtz(v.y, v.z);   // even idx, b32 write
            dst[3] = (_Float16)v.w;
        } else {                          // c == 56: last 2 floats wrap to next row
            dst[0] = (_Float16)v.x;
            dst[1] = (_Float16)v.y;
            int r2 = r + 1;
            int k2 = r2 / 58;
            int l2 = r2 - k2 * 58;
            _Float16* d2 = &lds[k2 * CH_STRIDE + l2 * LDS_STRIDE + 7];
            d2[0] = (_Float16)v.z;
            d2[1] = (_Float16)v.w;
        }
    }

    // ---- block-uniform shift multiplicities -> packed h2 weights in SGPRs
    float mhf[NK][5], mvf[NK][5], cntf[NK];
    #pragma unroll
    for (int k = 0; k < NK; ++k) {
        #pragma unroll
        for (int t = 0; t < 5; ++t) { mhf[k][t] = 0.f; mvf[k][t] = 0.f; }
        cntf[k] = 0.f;
        #pragma unroll
        for (int g = 0; g < 4; ++g) {
            int sh_v = pad_hv[(co * NK + k) * 8 + g];       // in {4,1,-2,-5,-8}
            int th   = (4 - sh_v) / 3;                      // slot 0..4
            int sv_v = pad_hv[(co * NK + k) * 8 + 4 + g];
            int tv   = (4 - sv_v) / 3;
            #pragma unroll
            for (int t = 0; t < 5; ++t) {
                mhf[k][t] += (th == t) ? 1.f : 0.f;
                mvf[k][t] += (tv == t) ? 1.f : 0.f;
            }
        }
    }
    #pragma unroll
    for (int g = 0; g < 4; ++g) {
        int c = idx_id[co * 4 + g] - co * NK;               // 0..4
        #pragma unroll
        for (int k = 0; k < NK; ++k) cntf[k] += (c == k) ? 1.f : 0.f;
    }
    unsigned int swh[NK][5], swv[NK][5], swc[NK];
    #pragma unroll
    for (int k = 0; k < NK; ++k) {
        #pragma unroll
        for (int t = 0; t < 5; ++t) {
            _Float16 a  = (_Float16)mhf[k][t];
            _Float16 b2 = (_Float16)mvf[k][t];
            h2 pa = {a, a}, pb = {b2, b2};
            swh[k][t] = __builtin_amdgcn_readfirstlane(h2u(pa));
            swv[k][t] = __builtin_amdgcn_readfirstlane(h2u(pb));
        }
        _Float16 cc = (_Float16)cntf[k];
        h2 pc = {cc, cc};
        swc[k] = __builtin_amdgcn_readfirstlane(h2u(pc));
    }

    __syncthreads();

    // ---- compute: one 8-px tile per thread, b64 + pk-FMA + uniform weight-skip
    const int q = tid;
    if (q < NTILE) {
        const int h  = q / 7;
        const int w0 = 8 * (q - h * 7);

        // v-tap rows, OOB redirected to the per-channel zero row (58)
        int voff[5];
        #pragma unroll
        for (int t = 0; t < 5; ++t) {
            int rr = h + 5 - 3 * t;
            int rv = ((unsigned)rr < 58u) ? rr : 58;
            voff[t] = rv * LDS_STRIDE + w0 + 8;
        }
        const int rowbase = (h + 1) * LDS_STRIDE + w0;

        h2 sh[4], sv[4], si[4];
        #pragma unroll
        for (int m = 0; m < 4; ++m) {
            sh[m] = h2{(_Float16)0.f, (_Float16)0.f};
            sv[m] = sh[m]; si[m] = sh[m];
        }

        #pragma unroll
        for (int k = 0; k < NK; ++k) {
            const _Float16* chp  = lds + k * CH_STRIDE;
            const _Float16* rowp = chp + rowbase;

            // 20-col window: 5 x ds_read_b64 -> 10 f16-pairs
            h2 H[10];
            #pragma unroll
            for (int m = 0; m < 5; ++m) {
                h4 w = *(const h4*)(rowp + 4 * m);
                __builtin_memcpy(&H[2 * m],     &w, 4);
                __builtin_memcpy(&H[2 * m + 1], (const char*)&w + 4, 4);
            }

            // out_h: tap t -> j = 12-3t (t even -> pair-aligned; t odd -> alignbit)
            // uniform skip: ~2.05 of 5 taps are zero-weight
            #pragma unroll
            for (int t = 0; t < 5; ++t) {
                unsigned int wbits = swh[k][t];
                if (wbits != 0u) {
                    h2 w2 = uh2(wbits);
                    int j = 12 - 3 * t;
                    if ((j & 1) == 0) {
                        int m0 = j >> 1;
                        #pragma unroll
                        for (int m = 0; m < 4; ++m) sh[m] += w2 * H[m0 + m];
                    } else {
                        int m0 = (j - 1) >> 1;
                        #pragma unroll
                        for (int m = 0; m < 4; ++m)
                            sh[m] += w2 * algn(H[m0 + m], H[m0 + m + 1]);
                    }
                }
            }

            // out_id: center cols 8..15 = H[4..7]
            if (swc[k] != 0u) {
                h2 c2 = uh2(swc[k]);
                #pragma unroll
                for (int m = 0; m < 4; ++m) si[m] += c2 * H[4 + m];
            }

            // out_v: 2 x b64 per NONZERO tap; OOB rows read the zero row
            #pragma unroll
            for (int t = 0; t < 5; ++t) {
                unsigned int wbits = swv[k][t];
                if (wbits != 0u) {
                    const _Float16* vp = chp + voff[t];
                    h4 a  = *(const h4*)(vp);
                    h4 b4 = *(const h4*)(vp + 4);
                    h2 V0, V1, V2, V3;
                    __builtin_memcpy(&V0, &a, 4);
                    __builtin_memcpy(&V1, (const char*)&a + 4, 4);
                    __builtin_memcpy(&V2, &b4, 4);
                    __builtin_memcpy(&V3, (const char*)&b4 + 4, 4);
                    h2 wv = uh2(wbits);
                    sv[0] += wv * V0; sv[1] += wv * V1;
                    sv[2] += wv * V2; sv[3] += wv * V3;
                }
            }
        }

        size_t o = (size_t)bc * NPIX + h * WOUT + w0;
        *(float4*)(out + o) =
            make_float4((float)sh[0].x, (float)sh[0].y, (float)sh[1].x, (float)sh[1].y);
        *(float4*)(out + o + 4) =
            make_float4((float)sh[2].x, (float)sh[2].y, (float)sh[3].x, (float)sh[3].y);
        *(float4*)(out + OUT_PLANE + o) =
            make_float4((float)sv[0].x, (float)sv[0].y, (float)sv[1].x, (float)sv[1].y);
        *(float4*)(out + OUT_PLANE + o + 4) =
            make_float4((float)sv[2].x, (float)sv[2].y, (float)sv[3].x, (float)sv[3].y);
        *(float4*)(out + 2 * OUT_PLANE + o) =
            make_float4((float)si[0].x, (float)si[0].y, (float)si[1].x, (float)si[1].y);
        *(float4*)(out + 2 * OUT_PLANE + o + 4) =
            make_float4((float)si[2].x, (float)si[2].y, (float)si[3].x, (float)si[3].y);
    }
}

extern "C" void kernel_launch(void* const* d_in, const int* in_sizes, int n_in,
                              void* d_out, int out_size, void* d_ws, size_t ws_size,
                              hipStream_t stream) {
    const float* x      = (const float*)d_in[0];
    const int*   pad_hv = (const int*)d_in[1];
    const int*   idx_id = (const int*)d_in[2];
    float*       out    = (float*)d_out;

    addshift_bb_kernel<<<dim3(BATCH * C_OUT_N), dim3(NTHREADS),
                         LDS_HALVES * 2, stream>>>(x, pad_hv, idx_id, out);
}